// Round 4
// baseline (188.700 us; speedup 1.0000x reference)
//
#include <hip/hip_runtime.h>

// MHSA matched-filter encode, bit-exact replication of the fp32 reference.
// Layout: 1 row per wave (block = 64 threads); window element j lives in
// lane (tid & 15); the 4 groups of 16 lanes hold identical replicas so all
// cross-lane reads can target group 0 (lanes 0..15).
//
// Exactness: the reference subtracts the whole filter from the window
// REPEATEDLY (win -= f per alive inner iteration) and accumulates err as a
// sequential fp32 prefix. We reproduce the identical op sequence: one
// v_sub per alive iteration on all lanes, err += readlane(term, r) in
// literal order. No reassociation anywhere.
//
// t = max(f-d, 0) is bit-equivalent to where(d<f, f-d, 0): a positive real
// difference rounds to >= +0, and for d>=f both forms contribute +/-0 whose
// addition to err (>= +0) is value-identical.

constexpr int NN = 2048;   // row length
constexpr int NBLK = 512;  // rows

__device__ __forceinline__ float f_readlane(float v, int lane) {
    return __int_as_float(__builtin_amdgcn_readlane(__float_as_int(v), lane));
}

// Slide window one element toward lane 0: lane i <- lane i+1 within each
// 16-lane DPP row (row_shl:1 = 0x101; cf. rocPRIM scans using row_shr for
// the opposite, prefix, direction); lane 15 (source lane 16 is outside the
// DPP row, bound_ctrl=false) keeps `fill` = the injected next element.
__device__ __forceinline__ float f_slide(float src, float fill) {
    return __int_as_float(__builtin_amdgcn_update_dpp(
        __float_as_int(fill), __float_as_int(src),
        0x101 /* row_shl:1 */, 0xF, 0xF, false));
}

__global__ __launch_bounds__(64) void mhsa_kernel(const float* __restrict__ data,
                                                  const float* __restrict__ filt,
                                                  float* __restrict__ out) {
    __shared__ float lrow[NN];
    const int row = blockIdx.x;
    const int tid = threadIdx.x;
    const int j = tid & 15;

    const float* rp = data + (size_t)row * NN;
    float* op = out + (size_t)row * NN;

    // Stage the whole row into LDS (read-only thereafter; the evolving
    // window state lives purely in registers).
    const float4* rp4 = (const float4*)rp;
    float4* l4 = (float4*)lrow;
#pragma unroll
    for (int k = 0; k < NN / 4 / 64; ++k)  // 8 x float4 per thread
        l4[tid + 64 * k] = rp4[tid + 64 * k];
    __syncthreads();

    const float fv = filt[j] * 0.2f;  // f = filter * NEW_AMP (exact, 1 mul)
    float v = lrow[j];                // window element j for step i=0

    // Steps i = 0 .. 2031 (all fits=true), in 16-step chunks.
    for (int ib = 0; ib < NN - 16; ib += 16) {
        unsigned obits = 0;
#pragma unroll
        for (int s = 0; s < 16; ++s) {
            // Issue the next-element broadcast read early; consumed only at
            // the slide after the (~100 cycle) inner loop.
            const float nxt = lrow[ib + 16 + s];

            // Inner loop, literal reference order.
            // j=0: err = max(f0 - win[0], 0); cond = err <= 0.5; out = cond
            // (err monotone nondecreasing => out == cond at j=0).
            // Then per alive j: decrement whole window by f (one exact
            // v_sub on all lanes), next term, re-check.
            float t = fmaxf(fv - v, 0.0f);
            float err = f_readlane(t, 0);
            if (err <= 0.5f) {
                obits |= (1u << s);
#pragma unroll
                for (int r = 1; r <= 16; ++r) {
                    v = v - fv;        // decrement #r (prev cond was true)
                    if (r == 16) break;  // j=15 cond true: decrement only
                    float tr = fmaxf(fv - v, 0.0f);
                    err += f_readlane(tr, r);
                    if (!(err <= 0.5f)) break;
                }
            }
            v = f_slide(v, nxt);  // window <- row[i+1 .. i+16]
        }
        // 16 outputs per chunk; groups 1..3 store duplicate values to the
        // same addresses (benign).
        op[ib + j] = ((obits >> j) & 1u) ? 1.0f : 0.0f;
    }

    // Step i = 2032 (last fits step, window = row[2032..2047]): output only,
    // no later step reads the row state.
    {
        float t = fmaxf(fv - v, 0.0f);
        float err = f_readlane(t, 0);
        float v0 = (err <= 0.5f) ? 1.0f : 0.0f;
        // i = 2033..2047: fits=false -> err stays 0 -> out = 1.
        op[(NN - 16) + j] = (j == 0) ? v0 : 1.0f;
    }
}

extern "C" void kernel_launch(void* const* d_in, const int* in_sizes, int n_in,
                              void* d_out, int out_size, void* d_ws, size_t ws_size,
                              hipStream_t stream) {
    const float* data = (const float*)d_in[0];  // [512, 2048] f32
    const float* filt = (const float*)d_in[1];  // [16] f32
    float* out = (float*)d_out;                 // [512, 2048] f32
    (void)in_sizes; (void)n_in; (void)out_size; (void)d_ws; (void)ws_size;
    mhsa_kernel<<<dim3(NBLK), dim3(64), 0, stream>>>(data, filt, out);
}